// Round 10
// baseline (199.709 us; speedup 1.0000x reference)
//
#include <hip/hip_runtime.h>
#include <hip/hip_bf16.h>
#include <cstddef>

// Problem constants (match reference)
constexpr int NN = 20000;   // nodes
constexpr int NE = 320000;  // edges
constexpr int NHEAD = 4;
constexpr int HD = 512;     // H*D
constexpr int MPAD = 20096; // 314*64 padded rows for GEMM tiles
constexpr int SLOTS = 64;   // padded-CSR slots per node (Poisson(16))
constexpr float NEG_SLOPE = 0.2f;

// MEASUREMENT ROUND: prep / logits / gather run their (idempotent) bodies
// TWICE internally so their true durations become visible in the top-5
// (2X > 43us fill threshold when X > ~22us).  memory clobber between passes
// prevents CSE.  Next round reverts REP to 1 and fixes what the counters show.
#define REP 2

using short8 = __attribute__((ext_vector_type(8))) short;
using f32x4 = __attribute__((ext_vector_type(4))) float;

// async global->LDS, 16B per lane, LDS dest = wave-uniform base + lane*16
__device__ inline void gload16(const void* g, void* l) {
  __builtin_amdgcn_global_load_lds(
      (const __attribute__((address_space(1))) void*)g,
      (__attribute__((address_space(3))) void*)l, 16, 0, 0);
}

__device__ inline float fastrcp(float x) { return __builtin_amdgcn_rcpf(x); }

// fast ELU negative branch: 3-inst vs ~30-inst expm1f
__device__ inline float fast_elu(float x) {
  return (x > 0.f) ? x : (__expf(x) - 1.0f);
}

// ---------------- fused prep (R8 layout; body repeated REP times) ------------
constexpr int S0 = NN;                      // cnt zero
constexpr int S1 = S0 + NN * 128 / 4;       // featsb (4 elems per item)
constexpr int S2 = S1 + 512 * 128;          // W1t
constexpr int S3 = S2 + 4 * 16 * 128;       // vcombh (8192)
constexpr int S4 = S3 + 1024;               // wl1t + wr1t (128*4 each)
constexpr int S5 = S4 + 60000;              // elq+er2 zero (NN*12 floats, x4)
constexpr int S6 = S5 + 256;                // partials zero
__global__ __launch_bounds__(256) void prep_kernel(
    const float* __restrict__ feats, const float* __restrict__ W1,
    const float* __restrict__ W2, const float* __restrict__ al1,
    const float* __restrict__ ar1, const float* __restrict__ al2,
    const float* __restrict__ ar2, const float* __restrict__ Wr,
    __hip_bfloat16* __restrict__ featsb, __hip_bfloat16* __restrict__ W1t,
    __hip_bfloat16* __restrict__ vcombh, float* __restrict__ wl1t,
    float* __restrict__ wr1t, float* __restrict__ zero3,
    float* __restrict__ partials, int* __restrict__ cnt) {
  int t = blockIdx.x * 256 + threadIdx.x;
  for (int rep = 0; rep < REP; ++rep) {
    if (t < S0) {
      cnt[t] = 0;
    } else if (t < S1) {
      int u = (t - S0) * 4;
      float4 f = *reinterpret_cast<const float4*>(&feats[u]);
      __hip_bfloat162 o0 = __float22bfloat162_rn(make_float2(f.x, f.y));
      __hip_bfloat162 o1 = __float22bfloat162_rn(make_float2(f.z, f.w));
      uint2 pk;
      pk.x = *reinterpret_cast<unsigned int*>(&o0);
      pk.y = *reinterpret_cast<unsigned int*>(&o1);
      *reinterpret_cast<uint2*>(&featsb[u]) = pk;
    } else if (t < S2) {
      int u = t - S1;                       // W1t[col][k]
      W1t[u] = __float2bfloat16(W1[(size_t)(u & 127) * 512 + (u >> 7)]);
    } else if (t < S3) {
      int u = t - S2;                       // vcombh[head][m][kk], swizzled
      int head = u >> 11, rem = u & 2047;
      int m = rem >> 7, kk = rem & 127;
      float s = 0.f;
      if (m < 12) {
        int h = m & 3;
        const float* vec = (m < 4) ? (al2 + h * 128)
                         : (m < 8) ? (ar2 + h * 128) : Wr;
        const float* wrow = W2 + (size_t)(head * 128 + kk) * 512 + h * 128;
        for (int d = 0; d < 128; ++d) s += wrow[d] * vec[d];
      }
      int slot = kk >> 3, e = kk & 7;
      int sl = slot ^ (m & 7);
      vcombh[head * 2048 + m * 128 + sl * 8 + e] = __float2bfloat16(s);
    } else if (t < S4) {
      int u = t - S3;                       // wl1t/wr1t[d][h]
      int d = u >> 3, rem = u & 7, h = rem >> 1, sel = rem & 1;
      const float* vec = (sel ? ar1 : al1) + h * 128;
      const float* wrow = W1 + (size_t)d * 512 + h * 128;
      float s = 0.f;
      for (int dd = 0; dd < 128; ++dd) s += wrow[dd] * vec[dd];
      (sel ? wr1t : wl1t)[d * 4 + h] = s;
    } else if (t < S5) {
      int u = (t - S4) * 4;                 // elq + er2 contiguous zero
      *reinterpret_cast<float4*>(&zero3[u]) = make_float4(0.f, 0.f, 0.f, 0.f);
    } else if (t < S6) {
      partials[t - S5] = 0.f;
    }
    asm volatile("" ::: "memory");          // force real re-execution
  }
}

// ---------------- CSR fill (once) + layer-1 logits (xREP) -------------------
__global__ __launch_bounds__(256) void fill_logits_kernel(
    const int* __restrict__ src, const int* __restrict__ dst,
    int* __restrict__ cnt, int* __restrict__ src_perm,
    const __hip_bfloat16* __restrict__ featsb,
    const float* __restrict__ wl1t, const float* __restrict__ wr1t,
    float* __restrict__ el1, float* __restrict__ er1) {
  int t = threadIdx.x;
  {
    int nth = gridDim.x * 256;
    int gid = blockIdx.x * 256 + t;
    for (int e = gid; e < NE; e += nth) {
      int d = dst[e];
      int p = atomicAdd(&cnt[d], 1);
      if (p < SLOTS) src_perm[d * SLOTS + p] = src[e];
    }
  }
  int wv = t >> 6, lane = t & 63;
  int half = lane >> 5, l5 = lane & 31;
  int n = blockIdx.x * 8 + wv * 2 + half;   // 2500*8 = 20000 exact
  int d0 = l5 * 4;
  for (int rep = 0; rep < REP; ++rep) {
    uint2 w = *reinterpret_cast<const uint2*>(&featsb[(size_t)n * 128 + d0]);
    __hip_bfloat162 u0 = *reinterpret_cast<__hip_bfloat162*>(&w.x);
    __hip_bfloat162 u1 = *reinterpret_cast<__hip_bfloat162*>(&w.y);
    float2 fA = __bfloat1622float2(u0);
    float2 fB = __bfloat1622float2(u1);
    float f[4] = {fA.x, fA.y, fB.x, fB.y};
    float pl[4] = {0.f, 0.f, 0.f, 0.f}, pr[4] = {0.f, 0.f, 0.f, 0.f};
#pragma unroll
    for (int j = 0; j < 4; ++j) {
      float4 wl = *reinterpret_cast<const float4*>(&wl1t[(d0 + j) * 4]);
      float4 wr = *reinterpret_cast<const float4*>(&wr1t[(d0 + j) * 4]);
      pl[0] += f[j] * wl.x; pl[1] += f[j] * wl.y;
      pl[2] += f[j] * wl.z; pl[3] += f[j] * wl.w;
      pr[0] += f[j] * wr.x; pr[1] += f[j] * wr.y;
      pr[2] += f[j] * wr.z; pr[3] += f[j] * wr.w;
    }
#pragma unroll
    for (int off = 1; off < 32; off <<= 1) {
#pragma unroll
      for (int k = 0; k < 4; ++k) {
        pl[k] += __shfl_xor(pl[k], off);
        pr[k] += __shfl_xor(pr[k], off);
      }
    }
    if (l5 == 0) {
      *reinterpret_cast<float4*>(&el1[n * 4]) =
          make_float4(pl[0], pl[1], pl[2], pl[3]);
      *reinterpret_cast<float4*>(&er1[n * 4]) =
          make_float4(pr[0], pr[1], pr[2], pr[3]);
    }
    asm volatile("" ::: "memory");
  }
}

// ---------------- layer-1 attention + FEATS aggregation (xREP) --------------
__global__ __launch_bounds__(256) void gather_kernel(
    const __hip_bfloat16* __restrict__ featsb,
    const int* __restrict__ cnt, const int* __restrict__ src_perm,
    const float* __restrict__ el, const float* __restrict__ er,
    __hip_bfloat16* __restrict__ aggb) {         // [MPAD][4*128] bf16
  __shared__ float4 alph[4][SLOTS];
  __shared__ int srcb[4][SLOTS];
  int wv = __builtin_amdgcn_readfirstlane((int)(threadIdx.x >> 6));
  int n = blockIdx.x * 4 + wv;
  int lane = threadIdx.x & 63;
  int c = min(cnt[n], SLOTS);

  for (int rep = 0; rep < REP; ++rep) {
    {
      float4 er4 = *reinterpret_cast<const float4*>(&er[n * 4]);
      float a0 = 0.f, a1 = 0.f, a2 = 0.f, a3 = 0.f;
      int sv = 0;
      if (lane < c) {
        sv = src_perm[n * SLOTS + lane];
        float4 e4 = *reinterpret_cast<const float4*>(&el[sv * 4]);
        float x0 = e4.x + er4.x, x1 = e4.y + er4.y;
        float x2 = e4.z + er4.z, x3 = e4.w + er4.w;
        x0 = (x0 > 0.f) ? x0 : NEG_SLOPE * x0;
        x1 = (x1 > 0.f) ? x1 : NEG_SLOPE * x1;
        x2 = (x2 > 0.f) ? x2 : NEG_SLOPE * x2;
        x3 = (x3 > 0.f) ? x3 : NEG_SLOPE * x3;
        a0 = __expf(x0); a1 = __expf(x1); a2 = __expf(x2); a3 = __expf(x3);
      }
      float s0 = a0, s1 = a1, s2 = a2, s3 = a3;
#pragma unroll
      for (int off = 1; off < 64; off <<= 1) {
        s0 += __shfl_xor(s0, off);
        s1 += __shfl_xor(s1, off);
        s2 += __shfl_xor(s2, off);
        s3 += __shfl_xor(s3, off);
      }
      float i0 = fastrcp(fmaxf(s0, 1e-9f));
      float i1 = fastrcp(fmaxf(s1, 1e-9f));
      float i2 = fastrcp(fmaxf(s2, 1e-9f));
      float i3 = fastrcp(fmaxf(s3, 1e-9f));
      alph[wv][lane] = make_float4(a0 * i0, a1 * i1, a2 * i2, a3 * i3);
      srcb[wv][lane] = sv;   // same-wave producer/consumer, no barrier
    }

    int half = lane >> 5, l5 = lane & 31;
    int d0 = l5 * 4;
    float acc[4][4] = {};   // [head][dim]

#define PR(I)                                                                  \
  {                                                                            \
    int e = (I) + half;                                                        \
    float4 a4 = alph[wv][e];                                                   \
    int s = srcb[wv][e];                                                       \
    uint2 w = *reinterpret_cast<const uint2*>(&featsb[(size_t)s * 128 + d0]);  \
    __hip_bfloat162 u0 = *reinterpret_cast<__hip_bfloat162*>(&w.x);            \
    __hip_bfloat162 u1 = *reinterpret_cast<__hip_bfloat162*>(&w.y);            \
    float2 fA = __bfloat1622float2(u0);                                        \
    float2 fB = __bfloat1622float2(u1);                                        \
    acc[0][0] += a4.x * fA.x; acc[0][1] += a4.x * fA.y;                        \
    acc[0][2] += a4.x * fB.x; acc[0][3] += a4.x * fB.y;                        \
    acc[1][0] += a4.y * fA.x; acc[1][1] += a4.y * fA.y;                        \
    acc[1][2] += a4.y * fB.x; acc[1][3] += a4.y * fB.y;                        \
    acc[2][0] += a4.z * fA.x; acc[2][1] += a4.z * fA.y;                        \
    acc[2][2] += a4.z * fB.x; acc[2][3] += a4.z * fB.y;                        \
    acc[3][0] += a4.w * fA.x; acc[3][1] += a4.w * fA.y;                        \
    acc[3][2] += a4.w * fB.x; acc[3][3] += a4.w * fB.y;                        \
  }

    int i = 0;
    for (; i + 3 < c; i += 4) { PR(i) PR(i + 2) }
    for (; i < c; i += 2) PR(i)
#undef PR

#pragma unroll
    for (int h = 0; h < 4; ++h)
#pragma unroll
      for (int j = 0; j < 4; ++j) acc[h][j] += __shfl_xor(acc[h][j], 32);

#pragma unroll
    for (int hh = 0; hh < 2; ++hh) {
      int h = half * 2 + hh;
      __hip_bfloat162 o0 =
          __float22bfloat162_rn(make_float2(acc[h][0], acc[h][1]));
      __hip_bfloat162 o1 =
          __float22bfloat162_rn(make_float2(acc[h][2], acc[h][3]));
      uint2 pk;
      pk.x = *reinterpret_cast<unsigned int*>(&o0);
      pk.y = *reinterpret_cast<unsigned int*>(&o1);
      *reinterpret_cast<uint2*>(&aggb[(size_t)n * HD + h * 128 + d0]) = pk;
    }
    asm volatile("" ::: "memory");
  }
}

// ---------------- h1 GEMM + MFMA 12-dot epilogue (R8-identical, no rep) -----
__global__ __launch_bounds__(256) void h1_gemm_kernel(
    const __hip_bfloat16* __restrict__ A,    // aggb [MPAD][512] bf16
    const __hip_bfloat16* __restrict__ Bt,   // W1t  [512][128] bf16
    const __hip_bfloat16* __restrict__ vcombh, // [4][16][128] bf16 pre-swizzled
    const float* __restrict__ b1,            // [512]
    float* __restrict__ elq,                 // [NN][8] el+q
    float* __restrict__ er2) {               // [NN][4]
  __shared__ short AsH[64 * 128];           // 16 KB: agg tile, then h1 tile
  __shared__ short Bs[128 * 128];           // 32 KB: W1t head-slice
  __shared__ short Vc[16 * 128];            // 4 KB: vcombh head-slice
  int t = threadIdx.x;
  int lane = t & 63, wave = t >> 6;
  int head = blockIdx.y;
  int nloc = lane & 15, quad = lane >> 4;

#pragma unroll
  for (int p = 0; p < 8; ++p) {             // B: 128 rows x 16 slots
    int fbase = p * 256 + wave * 64;
    int f = fbase + lane;
    int row = f >> 4, slot = f & 15;
    int ss = slot ^ (row & 7);
    gload16(Bt + (size_t)(head * 128 + row) * 128 + ss * 8, Bs + fbase * 8);
  }
  {
    int fbase = wave * 64;                  // Vc: pre-swizzled in global
    gload16(vcombh + head * 2048 + (size_t)(fbase + lane) * 8, Vc + fbase * 8);
  }

  for (int it = 0; it < 2; ++it) {
    int rowBase = (blockIdx.x * 2 + it) * 64;
    if (it) __syncthreads();   // all waves done reading AsH from prior tile

#pragma unroll
    for (int p = 0; p < 4; ++p) {           // A: 64 rows x 16 slots
      int fbase = p * 256 + wave * 64;
      int f = fbase + lane;
      int row = f >> 4, slot = f & 15;
      int ss = slot ^ (row & 7);
      gload16(A + (size_t)(rowBase + row) * HD + head * 128 + ss * 8,
              AsH + fbase * 8);
    }
    __syncthreads();   // staging (incl. B/Vc on first iter) complete

    f32x4 acc[8];
#pragma unroll
    for (int i = 0; i < 8; ++i) acc[i] = (f32x4){0.f, 0.f, 0.f, 0.f};
#pragma unroll
    for (int c = 0; c < 4; ++c) {
      int arow = wave * 16 + nloc;
      short8 bfr = *(const short8*)&AsH[arow * 128 +
                                        (((c << 2) + quad) ^ (arow & 7)) * 8];
#pragma unroll
      for (int i = 0; i < 8; ++i) {
        int brow = i * 16 + nloc;
        short8 af = *(const short8*)&Bs[brow * 128 +
                                        (((c << 2) + quad) ^ (brow & 7)) * 8];
        acc[i] = __builtin_amdgcn_mfma_f32_16x16x32_bf16(af, bfr, acc[i],
                                                         0, 0, 0);
      }
    }

    int node = wave * 16 + nloc;
#pragma unroll
    for (int i = 0; i < 8; ++i) {
      float4 b4 = *reinterpret_cast<const float4*>(
          &b1[head * 128 + i * 16 + quad * 4]);
      float e0 = fast_elu(acc[i][0] + b4.x);
      float e1 = fast_elu(acc[i][1] + b4.y);
      float e2 = fast_elu(acc[i][2] + b4.z);
      float e3 = fast_elu(acc[i][3] + b4.w);
      __hip_bfloat162 p0 = __float22bfloat162_rn(make_float2(e0, e1));
      __hip_bfloat162 p1 = __float22bfloat162_rn(make_float2(e2, e3));
      uint2 pk;
      pk.x = *reinterpret_cast<unsigned int*>(&p0);
      pk.y = *reinterpret_cast<unsigned int*>(&p1);
      int slot = i * 2 + (quad >> 1);
      int sub = quad & 1;
      int sl = slot ^ (node & 7);
      *reinterpret_cast<uint2*>(&AsH[node * 128 + sl * 8 + sub * 4]) = pk;
    }

    f32x4 acc2 = (f32x4){0.f, 0.f, 0.f, 0.f};
#pragma unroll
    for (int c = 0; c < 4; ++c) {
      short8 a2 = *(const short8*)&Vc[nloc * 128 +
                                      (((c << 2) + quad) ^ (nloc & 7)) * 8];
      short8 b2v = *(const short8*)&AsH[node * 128 +
                                        (((c << 2) + quad) ^ (node & 7)) * 8];
      acc2 = __builtin_amdgcn_mfma_f32_16x16x32_bf16(a2, b2v, acc2, 0, 0, 0);
    }

    int gn = rowBase + node;
    if (gn < NN) {
      if (quad == 0) {
#pragma unroll
        for (int r = 0; r < 4; ++r)
          atomicAdd(&elq[(size_t)gn * 8 + r], acc2[r]);
      } else if (quad == 1) {
#pragma unroll
        for (int r = 0; r < 4; ++r)
          atomicAdd(&er2[(size_t)gn * 4 + r], acc2[r]);
      } else if (quad == 2) {
#pragma unroll
        for (int r = 0; r < 4; ++r)
          atomicAdd(&elq[(size_t)gn * 8 + 4 + r], acc2[r]);
      }
    }
  }
}

// ---------------- layer-2 attention + readout dot (R8-identical) ------------
__global__ __launch_bounds__(256) void attn_q_kernel(
    const int* __restrict__ src_perm,
    const int* __restrict__ cnt,
    const float* __restrict__ elq,          // [NN][8]
    const float* __restrict__ er2,          // [NN][4]
    float* __restrict__ partials) {         // [256]
  __shared__ float blk[4];
  int wv = __builtin_amdgcn_readfirstlane((int)(threadIdx.x >> 6));
  int n = blockIdx.x * 4 + wv;
  int lane = threadIdx.x & 63;
  int c = min(cnt[n], SLOTS);
  float4 er4 = *reinterpret_cast<const float4*>(&er2[n * 4]);
  float a0 = 0.f, a1 = 0.f, a2 = 0.f, a3 = 0.f;
  float4 q4 = make_float4(0.f, 0.f, 0.f, 0.f);
  if (lane < c) {
    int s = src_perm[n * SLOTS + lane];
    float4 e4 = *reinterpret_cast<const float4*>(&elq[(size_t)s * 8]);
    q4 = *reinterpret_cast<const float4*>(&elq[(size_t)s * 8 + 4]);
    float x0 = e4.x + er4.x, x1 = e4.y + er4.y;
    float x2 = e4.z + er4.z, x3 = e4.w + er4.w;
    x0 = (x0 > 0.f) ? x0 : NEG_SLOPE * x0;
    x1 = (x1 > 0.f) ? x1 : NEG_SLOPE * x1;
    x2 = (x2 > 0.f) ? x2 : NEG_SLOPE * x2;
    x3 = (x3 > 0.f) ? x3 : NEG_SLOPE * x3;
    a0 = __expf(x0); a1 = __expf(x1); a2 = __expf(x2); a3 = __expf(x3);
  }
  float s0 = a0, s1 = a1, s2 = a2, s3 = a3;
#pragma unroll
  for (int off = 1; off < 64; off <<= 1) {
    s0 += __shfl_xor(s0, off);
    s1 += __shfl_xor(s1, off);
    s2 += __shfl_xor(s2, off);
    s3 += __shfl_xor(s3, off);
  }
  float p = 0.f;
  if (lane < c) {
    p = (a0 * fastrcp(fmaxf(s0, 1e-9f))) * q4.x +
        (a1 * fastrcp(fmaxf(s1, 1e-9f))) * q4.y +
        (a2 * fastrcp(fmaxf(s2, 1e-9f))) * q4.z +
        (a3 * fastrcp(fmaxf(s3, 1e-9f))) * q4.w;
  }
#pragma unroll
  for (int off = 32; off > 0; off >>= 1) p += __shfl_down(p, off);
  if (lane == 0) blk[wv] = p;
  __syncthreads();
  if (threadIdx.x == 0) {
    atomicAdd(&partials[blockIdx.x & 255], blk[0] + blk[1] + blk[2] + blk[3]);
  }
}

// ---------------- final: out = 0.25*(sum partials + NN*b2.Wr_rep) + NN*br ----
__global__ __launch_bounds__(512) void final_kernel(
    const float* __restrict__ partials, const float* __restrict__ b2,
    const float* __restrict__ Wr, const float* __restrict__ br,
    float* __restrict__ out) {
  __shared__ float tmp[512];
  int t = threadIdx.x;
  float sum = (t < 256) ? partials[t] : 0.f;
  sum += (float)NN * b2[t] * Wr[t & 127];
  tmp[t] = sum;
  __syncthreads();
  for (int off = 256; off > 0; off >>= 1) {
    if (t < off) tmp[t] += tmp[t + off];
    __syncthreads();
  }
  if (t == 0) out[0] = 0.25f * tmp[0] + (float)NN * br[0];
}

// ---------------- launch ----------------
extern "C" void kernel_launch(void* const* d_in, const int* in_sizes, int n_in,
                              void* d_out, int out_size, void* d_ws, size_t ws_size,
                              hipStream_t stream) {
  const float* feats = (const float*)d_in[0];
  const int* src = (const int*)d_in[1];
  const int* dst = (const int*)d_in[2];
  const float* W1 = (const float*)d_in[3];
  const float* al1 = (const float*)d_in[4];
  const float* ar1 = (const float*)d_in[5];
  const float* b1 = (const float*)d_in[6];
  const float* W2 = (const float*)d_in[7];
  const float* al2 = (const float*)d_in[8];
  const float* ar2 = (const float*)d_in[9];
  const float* b2 = (const float*)d_in[10];
  const float* Wr = (const float*)d_in[11];
  const float* br = (const float*)d_in[12];
  float* out = (float*)d_out;

  // workspace layout (~33 MB); all section sizes multiples of 16 B
  __hip_bfloat16* featsb = (__hip_bfloat16*)d_ws;               // NN*128 bf16
  __hip_bfloat16* aggb = featsb + (size_t)NN * 128;             // MPAD*512 bf16
  __hip_bfloat16* W1t = aggb + (size_t)MPAD * HD;               // 512*128 bf16
  __hip_bfloat16* vcombh = W1t + 512 * 128;                     // 4*16*128 bf16
  float* wl1t = (float*)(vcombh + 4 * 16 * 128);                // 128*4 f32
  float* wr1t = wl1t + 512;                                     // 128*4 f32
  float* el1 = wr1t + 512;                                      // NN*4
  float* er1 = el1 + (size_t)NN * NHEAD;                        // NN*4
  float* elq = er1 + (size_t)NN * NHEAD;                        // NN*8
  float* er2 = elq + (size_t)NN * 8;                            // NN*4
  float* partials = er2 + (size_t)NN * NHEAD;                   // 256
  int* cnt = (int*)(partials + 256);                            // NN
  int* src_perm = cnt + NN;                                     // NN*SLOTS

  // prep: cnt zero + feats->bf16 + W1^T + vcombh + wl1t/wr1t + zeros
  prep_kernel<<<(S6 + 255) / 256, 256, 0, stream>>>(
      feats, W1, W2, al1, ar1, al2, ar2, Wr, featsb, W1t, vcombh, wl1t, wr1t,
      elq, partials, cnt);

  // CSR fill + layer-1 logits
  fill_logits_kernel<<<NN / 8, 256, 0, stream>>>(
      src, dst, cnt, src_perm, featsb, wl1t, wr1t, el1, er1);

  // layer-1 attn + FEATS aggregation
  gather_kernel<<<NN / 4, 256, 0, stream>>>(featsb, cnt, src_perm, el1, er1,
                                            aggb);

  // agg @ W1 -> h1 (in-LDS) -> atomic combine into compact elq/er2
  dim3 h1grid(MPAD / 128, NHEAD);
  h1_gemm_kernel<<<h1grid, 256, 0, stream>>>(aggb, W1t, vcombh, b1, elq, er2);

  // layer-2 attention + readout dot; spread partials then tiny final reduce
  attn_q_kernel<<<NN / 4, 256, 0, stream>>>(src_perm, cnt, elq, er2, partials);
  final_kernel<<<1, 512, 0, stream>>>(partials, b2, Wr, br, out);
}

// Round 11
// 172.235 us; speedup vs baseline: 1.1595x; 1.1595x over previous
//
#include <hip/hip_runtime.h>
#include <hip/hip_bf16.h>
#include <cstddef>

// Problem constants (match reference)
constexpr int NN = 20000;   // nodes
constexpr int NE = 320000;  // edges
constexpr int NHEAD = 4;
constexpr int HD = 512;     // H*D
constexpr int MPAD = 20096; // 314*64 padded rows for GEMM tiles
constexpr int SLOTS = 64;   // padded-CSR slots per node (Poisson(16))
constexpr float NEG_SLOPE = 0.2f;

using short8 = __attribute__((ext_vector_type(8))) short;
using f32x4 = __attribute__((ext_vector_type(4))) float;
using f32x2v = __attribute__((ext_vector_type(2))) float;

// async global->LDS, 16B per lane, LDS dest = wave-uniform base + lane*16
__device__ inline void gload16(const void* g, void* l) {
  __builtin_amdgcn_global_load_lds(
      (const __attribute__((address_space(1))) void*)g,
      (__attribute__((address_space(3))) void*)l, 16, 0, 0);
}

__device__ inline float fastrcp(float x) { return __builtin_amdgcn_rcpf(x); }

// fast ELU negative branch: 3-inst vs ~30-inst expm1f
__device__ inline float fast_elu(float x) {
  return (x > 0.f) ? x : (__expf(x) - 1.0f);
}

// ---------------- fused prep (R8-identical) ----------------------------------
constexpr int S0 = NN;                      // cnt zero
constexpr int S1 = S0 + NN * 128 / 4;       // featsb (4 elems per item)
constexpr int S2 = S1 + 512 * 128;          // W1t
constexpr int S3 = S2 + 4 * 16 * 128;       // vcombh (8192)
constexpr int S4 = S3 + 1024;               // wl1t + wr1t (128*4 each)
constexpr int S5 = S4 + 60000;              // elq+er2 zero (NN*12 floats, x4)
constexpr int S6 = S5 + 256;                // partials zero
__global__ __launch_bounds__(256) void prep_kernel(
    const float* __restrict__ feats, const float* __restrict__ W1,
    const float* __restrict__ W2, const float* __restrict__ al1,
    const float* __restrict__ ar1, const float* __restrict__ al2,
    const float* __restrict__ ar2, const float* __restrict__ Wr,
    __hip_bfloat16* __restrict__ featsb, __hip_bfloat16* __restrict__ W1t,
    __hip_bfloat16* __restrict__ vcombh, float* __restrict__ wl1t,
    float* __restrict__ wr1t, float* __restrict__ zero3,
    float* __restrict__ partials, int* __restrict__ cnt) {
  int t = blockIdx.x * 256 + threadIdx.x;
  if (t < S0) {
    cnt[t] = 0;
  } else if (t < S1) {
    int u = (t - S0) * 4;
    float4 f = *reinterpret_cast<const float4*>(&feats[u]);
    __hip_bfloat162 o0 = __float22bfloat162_rn(make_float2(f.x, f.y));
    __hip_bfloat162 o1 = __float22bfloat162_rn(make_float2(f.z, f.w));
    uint2 pk;
    pk.x = *reinterpret_cast<unsigned int*>(&o0);
    pk.y = *reinterpret_cast<unsigned int*>(&o1);
    *reinterpret_cast<uint2*>(&featsb[u]) = pk;
  } else if (t < S2) {
    int u = t - S1;                       // W1t[col][k]
    W1t[u] = __float2bfloat16(W1[(size_t)(u & 127) * 512 + (u >> 7)]);
  } else if (t < S3) {
    int u = t - S2;                       // vcombh[head][m][kk], swizzled
    int head = u >> 11, rem = u & 2047;
    int m = rem >> 7, kk = rem & 127;
    float s = 0.f;
    if (m < 12) {
      int h = m & 3;
      const float* vec = (m < 4) ? (al2 + h * 128)
                       : (m < 8) ? (ar2 + h * 128) : Wr;
      const float* wrow = W2 + (size_t)(head * 128 + kk) * 512 + h * 128;
      for (int d = 0; d < 128; ++d) s += wrow[d] * vec[d];
    }
    int slot = kk >> 3, e = kk & 7;
    int sl = slot ^ (m & 7);
    vcombh[head * 2048 + m * 128 + sl * 8 + e] = __float2bfloat16(s);
  } else if (t < S4) {
    int u = t - S3;                       // wl1t/wr1t[d][h]
    int d = u >> 3, rem = u & 7, h = rem >> 1, sel = rem & 1;
    const float* vec = (sel ? ar1 : al1) + h * 128;
    const float* wrow = W1 + (size_t)d * 512 + h * 128;
    float s = 0.f;
    for (int dd = 0; dd < 128; ++dd) s += wrow[dd] * vec[dd];
    (sel ? wr1t : wl1t)[d * 4 + h] = s;
  } else if (t < S5) {
    int u = (t - S4) * 4;                 // elq + er2 contiguous zero
    *reinterpret_cast<float4*>(&zero3[u]) = make_float4(0.f, 0.f, 0.f, 0.f);
  } else if (t < S6) {
    partials[t - S5] = 0.f;
  }
}

// ---------------- CSR fill + layer-1 logits (R8-identical) ------------------
__global__ __launch_bounds__(256) void fill_logits_kernel(
    const int* __restrict__ src, const int* __restrict__ dst,
    int* __restrict__ cnt, int* __restrict__ src_perm,
    const __hip_bfloat16* __restrict__ featsb,
    const float* __restrict__ wl1t, const float* __restrict__ wr1t,
    float* __restrict__ el1, float* __restrict__ er1) {
  int t = threadIdx.x;
  {
    int nth = gridDim.x * 256;
    int gid = blockIdx.x * 256 + t;
    for (int e = gid; e < NE; e += nth) {
      int d = dst[e];
      int p = atomicAdd(&cnt[d], 1);
      if (p < SLOTS) src_perm[d * SLOTS + p] = src[e];
    }
  }
  int wv = t >> 6, lane = t & 63;
  int half = lane >> 5, l5 = lane & 31;
  int n = blockIdx.x * 8 + wv * 2 + half;   // 2500*8 = 20000 exact
  int d0 = l5 * 4;
  uint2 w = *reinterpret_cast<const uint2*>(&featsb[(size_t)n * 128 + d0]);
  __hip_bfloat162 u0 = *reinterpret_cast<__hip_bfloat162*>(&w.x);
  __hip_bfloat162 u1 = *reinterpret_cast<__hip_bfloat162*>(&w.y);
  float2 fA = __bfloat1622float2(u0);
  float2 fB = __bfloat1622float2(u1);
  float f[4] = {fA.x, fA.y, fB.x, fB.y};
  float pl[4] = {0.f, 0.f, 0.f, 0.f}, pr[4] = {0.f, 0.f, 0.f, 0.f};
#pragma unroll
  for (int j = 0; j < 4; ++j) {
    float4 wl = *reinterpret_cast<const float4*>(&wl1t[(d0 + j) * 4]);
    float4 wr = *reinterpret_cast<const float4*>(&wr1t[(d0 + j) * 4]);
    pl[0] += f[j] * wl.x; pl[1] += f[j] * wl.y;
    pl[2] += f[j] * wl.z; pl[3] += f[j] * wl.w;
    pr[0] += f[j] * wr.x; pr[1] += f[j] * wr.y;
    pr[2] += f[j] * wr.z; pr[3] += f[j] * wr.w;
  }
#pragma unroll
  for (int off = 1; off < 32; off <<= 1) {
#pragma unroll
    for (int k = 0; k < 4; ++k) {
      pl[k] += __shfl_xor(pl[k], off);
      pr[k] += __shfl_xor(pr[k], off);
    }
  }
  if (l5 == 0) {
    *reinterpret_cast<float4*>(&el1[n * 4]) =
        make_float4(pl[0], pl[1], pl[2], pl[3]);
    *reinterpret_cast<float4*>(&er1[n * 4]) =
        make_float4(pr[0], pr[1], pr[2], pr[3]);
  }
}

// ---------------- layer-1 attention + FEATS aggregation ---------------------
// R10 measurement: this kernel is 22us and VALU-BOUND (VALUBusy 72-75%, HBM
// 18%, 0 bank conflicts).  The FMA floor is 8 wave-inst/edge (16 scalar
// v_fmac per 2-edge PR).  Fix: packed-f32 math — accumulate with
// ext_vector<2> float so LLVM selects v_pk_fma_f32 (2 FMA/inst on CDNA),
// with alphas PRE-SPLATTED to (a,a) pairs in LDS during phase 1 so phase 2
// needs no broadcast movs.  Same f32 ops in the same order -> bit-identical.
__global__ __launch_bounds__(256) void gather_kernel(
    const __hip_bfloat16* __restrict__ featsb,
    const int* __restrict__ cnt, const int* __restrict__ src_perm,
    const float* __restrict__ el, const float* __restrict__ er,
    __hip_bfloat16* __restrict__ aggb) {         // [MPAD][4*128] bf16
  __shared__ f32x2v alph2[4][SLOTS][4];          // (a,a) per head, 8 KB
  __shared__ int srcb[4][SLOTS];
  int wv = __builtin_amdgcn_readfirstlane((int)(threadIdx.x >> 6));
  int n = blockIdx.x * 4 + wv;
  int lane = threadIdx.x & 63;
  int c = min(cnt[n], SLOTS);

  // ---- phase 1: attention coefficients (lane = slot), splatted pairs ----
  {
    float4 er4 = *reinterpret_cast<const float4*>(&er[n * 4]);
    float a0 = 0.f, a1 = 0.f, a2 = 0.f, a3 = 0.f;
    int sv = 0;
    if (lane < c) {
      sv = src_perm[n * SLOTS + lane];
      float4 e4 = *reinterpret_cast<const float4*>(&el[sv * 4]);
      float x0 = e4.x + er4.x, x1 = e4.y + er4.y;
      float x2 = e4.z + er4.z, x3 = e4.w + er4.w;
      x0 = (x0 > 0.f) ? x0 : NEG_SLOPE * x0;
      x1 = (x1 > 0.f) ? x1 : NEG_SLOPE * x1;
      x2 = (x2 > 0.f) ? x2 : NEG_SLOPE * x2;
      x3 = (x3 > 0.f) ? x3 : NEG_SLOPE * x3;
      a0 = __expf(x0); a1 = __expf(x1); a2 = __expf(x2); a3 = __expf(x3);
    }
    float s0 = a0, s1 = a1, s2 = a2, s3 = a3;
#pragma unroll
    for (int off = 1; off < 64; off <<= 1) {
      s0 += __shfl_xor(s0, off);
      s1 += __shfl_xor(s1, off);
      s2 += __shfl_xor(s2, off);
      s3 += __shfl_xor(s3, off);
    }
    float v0 = a0 * fastrcp(fmaxf(s0, 1e-9f));
    float v1 = a1 * fastrcp(fmaxf(s1, 1e-9f));
    float v2 = a2 * fastrcp(fmaxf(s2, 1e-9f));
    float v3 = a3 * fastrcp(fmaxf(s3, 1e-9f));
    alph2[wv][lane][0] = (f32x2v){v0, v0};
    alph2[wv][lane][1] = (f32x2v){v1, v1};
    alph2[wv][lane][2] = (f32x2v){v2, v2};
    alph2[wv][lane][3] = (f32x2v){v3, v3};
    srcb[wv][lane] = sv;   // same-wave producer/consumer, no barrier
  }

  // ---- phase 2: gather, half-wave = one edge, 4 dims (8B) per lane ----
  int half = lane >> 5, l5 = lane & 31;
  int d0 = l5 * 4;
  f32x2v accA[4], accB[4];   // [head] x {dims d0,d0+1} / {d0+2,d0+3}
#pragma unroll
  for (int h = 0; h < 4; ++h) {
    accA[h] = (f32x2v){0.f, 0.f};
    accB[h] = (f32x2v){0.f, 0.f};
  }

#define PR(I)                                                                  \
  {                                                                            \
    int e = (I) + half;                                                        \
    int s = srcb[wv][e];                                                       \
    f32x2v aa0 = alph2[wv][e][0], aa1 = alph2[wv][e][1];                       \
    f32x2v aa2 = alph2[wv][e][2], aa3 = alph2[wv][e][3];                       \
    uint2 w = *reinterpret_cast<const uint2*>(&featsb[(size_t)s * 128 + d0]);  \
    __hip_bfloat162 u0 = *reinterpret_cast<__hip_bfloat162*>(&w.x);            \
    __hip_bfloat162 u1 = *reinterpret_cast<__hip_bfloat162*>(&w.y);            \
    float2 t0 = __bfloat1622float2(u0);                                        \
    float2 t1 = __bfloat1622float2(u1);                                        \
    f32x2v fA = (f32x2v){t0.x, t0.y};                                          \
    f32x2v fB = (f32x2v){t1.x, t1.y};                                          \
    accA[0] += aa0 * fA; accB[0] += aa0 * fB;                                  \
    accA[1] += aa1 * fA; accB[1] += aa1 * fB;                                  \
    accA[2] += aa2 * fA; accB[2] += aa2 * fB;                                  \
    accA[3] += aa3 * fA; accB[3] += aa3 * fB;                                  \
  }

  int i = 0;
  for (; i + 3 < c; i += 4) { PR(i) PR(i + 2) }
  for (; i < c; i += 2) PR(i)
#undef PR

  // combine the two halves (each lane then holds full sums for its 4 dims)
#pragma unroll
  for (int h = 0; h < 4; ++h) {
    accA[h].x += __shfl_xor(accA[h].x, 32);
    accA[h].y += __shfl_xor(accA[h].y, 32);
    accB[h].x += __shfl_xor(accB[h].x, 32);
    accB[h].y += __shfl_xor(accB[h].y, 32);
  }

  // store: half 0 writes heads 0-1, half 1 writes heads 2-3 (8B each)
#pragma unroll
  for (int hh = 0; hh < 2; ++hh) {
    int h = half * 2 + hh;
    __hip_bfloat162 o0 =
        __float22bfloat162_rn(make_float2(accA[h].x, accA[h].y));
    __hip_bfloat162 o1 =
        __float22bfloat162_rn(make_float2(accB[h].x, accB[h].y));
    uint2 pk;
    pk.x = *reinterpret_cast<unsigned int*>(&o0);
    pk.y = *reinterpret_cast<unsigned int*>(&o1);
    *reinterpret_cast<uint2*>(&aggb[(size_t)n * HD + h * 128 + d0]) = pk;
  }
}

// ---------------- h1 GEMM + MFMA 12-dot epilogue (R8-identical) -------------
__global__ __launch_bounds__(256) void h1_gemm_kernel(
    const __hip_bfloat16* __restrict__ A,    // aggb [MPAD][512] bf16
    const __hip_bfloat16* __restrict__ Bt,   // W1t  [512][128] bf16
    const __hip_bfloat16* __restrict__ vcombh, // [4][16][128] bf16 pre-swizzled
    const float* __restrict__ b1,            // [512]
    float* __restrict__ elq,                 // [NN][8] el+q
    float* __restrict__ er2) {               // [NN][4]
  __shared__ short AsH[64 * 128];           // 16 KB: agg tile, then h1 tile
  __shared__ short Bs[128 * 128];           // 32 KB: W1t head-slice
  __shared__ short Vc[16 * 128];            // 4 KB: vcombh head-slice
  int t = threadIdx.x;
  int lane = t & 63, wave = t >> 6;
  int head = blockIdx.y;
  int nloc = lane & 15, quad = lane >> 4;

#pragma unroll
  for (int p = 0; p < 8; ++p) {             // B: 128 rows x 16 slots
    int fbase = p * 256 + wave * 64;
    int f = fbase + lane;
    int row = f >> 4, slot = f & 15;
    int ss = slot ^ (row & 7);
    gload16(Bt + (size_t)(head * 128 + row) * 128 + ss * 8, Bs + fbase * 8);
  }
  {
    int fbase = wave * 64;                  // Vc: pre-swizzled in global
    gload16(vcombh + head * 2048 + (size_t)(fbase + lane) * 8, Vc + fbase * 8);
  }

  for (int it = 0; it < 2; ++it) {
    int rowBase = (blockIdx.x * 2 + it) * 64;
    if (it) __syncthreads();   // all waves done reading AsH from prior tile

#pragma unroll
    for (int p = 0; p < 4; ++p) {           // A: 64 rows x 16 slots
      int fbase = p * 256 + wave * 64;
      int f = fbase + lane;
      int row = f >> 4, slot = f & 15;
      int ss = slot ^ (row & 7);
      gload16(A + (size_t)(rowBase + row) * HD + head * 128 + ss * 8,
              AsH + fbase * 8);
    }
    __syncthreads();   // staging (incl. B/Vc on first iter) complete

    f32x4 acc[8];
#pragma unroll
    for (int i = 0; i < 8; ++i) acc[i] = (f32x4){0.f, 0.f, 0.f, 0.f};
#pragma unroll
    for (int c = 0; c < 4; ++c) {
      int arow = wave * 16 + nloc;
      short8 bfr = *(const short8*)&AsH[arow * 128 +
                                        (((c << 2) + quad) ^ (arow & 7)) * 8];
#pragma unroll
      for (int i = 0; i < 8; ++i) {
        int brow = i * 16 + nloc;
        short8 af = *(const short8*)&Bs[brow * 128 +
                                        (((c << 2) + quad) ^ (brow & 7)) * 8];
        acc[i] = __builtin_amdgcn_mfma_f32_16x16x32_bf16(af, bfr, acc[i],
                                                         0, 0, 0);
      }
    }

    int node = wave * 16 + nloc;
#pragma unroll
    for (int i = 0; i < 8; ++i) {
      float4 b4 = *reinterpret_cast<const float4*>(
          &b1[head * 128 + i * 16 + quad * 4]);
      float e0 = fast_elu(acc[i][0] + b4.x);
      float e1 = fast_elu(acc[i][1] + b4.y);
      float e2 = fast_elu(acc[i][2] + b4.z);
      float e3 = fast_elu(acc[i][3] + b4.w);
      __hip_bfloat162 p0 = __float22bfloat162_rn(make_float2(e0, e1));
      __hip_bfloat162 p1 = __float22bfloat162_rn(make_float2(e2, e3));
      uint2 pk;
      pk.x = *reinterpret_cast<unsigned int*>(&p0);
      pk.y = *reinterpret_cast<unsigned int*>(&p1);
      int slot = i * 2 + (quad >> 1);
      int sub = quad & 1;
      int sl = slot ^ (node & 7);
      *reinterpret_cast<uint2*>(&AsH[node * 128 + sl * 8 + sub * 4]) = pk;
    }

    f32x4 acc2 = (f32x4){0.f, 0.f, 0.f, 0.f};
#pragma unroll
    for (int c = 0; c < 4; ++c) {
      short8 a2 = *(const short8*)&Vc[nloc * 128 +
                                      (((c << 2) + quad) ^ (nloc & 7)) * 8];
      short8 b2v = *(const short8*)&AsH[node * 128 +
                                        (((c << 2) + quad) ^ (node & 7)) * 8];
      acc2 = __builtin_amdgcn_mfma_f32_16x16x32_bf16(a2, b2v, acc2, 0, 0, 0);
    }

    int gn = rowBase + node;
    if (gn < NN) {
      if (quad == 0) {
#pragma unroll
        for (int r = 0; r < 4; ++r)
          atomicAdd(&elq[(size_t)gn * 8 + r], acc2[r]);
      } else if (quad == 1) {
#pragma unroll
        for (int r = 0; r < 4; ++r)
          atomicAdd(&er2[(size_t)gn * 4 + r], acc2[r]);
      } else if (quad == 2) {
#pragma unroll
        for (int r = 0; r < 4; ++r)
          atomicAdd(&elq[(size_t)gn * 8 + 4 + r], acc2[r]);
      }
    }
  }
}

// ---------------- layer-2 attention + readout dot (R8-identical) ------------
__global__ __launch_bounds__(256) void attn_q_kernel(
    const int* __restrict__ src_perm,
    const int* __restrict__ cnt,
    const float* __restrict__ elq,          // [NN][8]
    const float* __restrict__ er2,          // [NN][4]
    float* __restrict__ partials) {         // [256]
  __shared__ float blk[4];
  int wv = __builtin_amdgcn_readfirstlane((int)(threadIdx.x >> 6));
  int n = blockIdx.x * 4 + wv;
  int lane = threadIdx.x & 63;
  int c = min(cnt[n], SLOTS);
  float4 er4 = *reinterpret_cast<const float4*>(&er2[n * 4]);
  float a0 = 0.f, a1 = 0.f, a2 = 0.f, a3 = 0.f;
  float4 q4 = make_float4(0.f, 0.f, 0.f, 0.f);
  if (lane < c) {
    int s = src_perm[n * SLOTS + lane];
    float4 e4 = *reinterpret_cast<const float4*>(&elq[(size_t)s * 8]);
    q4 = *reinterpret_cast<const float4*>(&elq[(size_t)s * 8 + 4]);
    float x0 = e4.x + er4.x, x1 = e4.y + er4.y;
    float x2 = e4.z + er4.z, x3 = e4.w + er4.w;
    x0 = (x0 > 0.f) ? x0 : NEG_SLOPE * x0;
    x1 = (x1 > 0.f) ? x1 : NEG_SLOPE * x1;
    x2 = (x2 > 0.f) ? x2 : NEG_SLOPE * x2;
    x3 = (x3 > 0.f) ? x3 : NEG_SLOPE * x3;
    a0 = __expf(x0); a1 = __expf(x1); a2 = __expf(x2); a3 = __expf(x3);
  }
  float s0 = a0, s1 = a1, s2 = a2, s3 = a3;
#pragma unroll
  for (int off = 1; off < 64; off <<= 1) {
    s0 += __shfl_xor(s0, off);
    s1 += __shfl_xor(s1, off);
    s2 += __shfl_xor(s2, off);
    s3 += __shfl_xor(s3, off);
  }
  float p = 0.f;
  if (lane < c) {
    p = (a0 * fastrcp(fmaxf(s0, 1e-9f))) * q4.x +
        (a1 * fastrcp(fmaxf(s1, 1e-9f))) * q4.y +
        (a2 * fastrcp(fmaxf(s2, 1e-9f))) * q4.z +
        (a3 * fastrcp(fmaxf(s3, 1e-9f))) * q4.w;
  }
#pragma unroll
  for (int off = 32; off > 0; off >>= 1) p += __shfl_down(p, off);
  if (lane == 0) blk[wv] = p;
  __syncthreads();
  if (threadIdx.x == 0) {
    atomicAdd(&partials[blockIdx.x & 255], blk[0] + blk[1] + blk[2] + blk[3]);
  }
}

// ---------------- final: out = 0.25*(sum partials + NN*b2.Wr_rep) + NN*br ----
__global__ __launch_bounds__(512) void final_kernel(
    const float* __restrict__ partials, const float* __restrict__ b2,
    const float* __restrict__ Wr, const float* __restrict__ br,
    float* __restrict__ out) {
  __shared__ float tmp[512];
  int t = threadIdx.x;
  float sum = (t < 256) ? partials[t] : 0.f;
  sum += (float)NN * b2[t] * Wr[t & 127];
  tmp[t] = sum;
  __syncthreads();
  for (int off = 256; off > 0; off >>= 1) {
    if (t < off) tmp[t] += tmp[t + off];
    __syncthreads();
  }
  if (t == 0) out[0] = 0.25f * tmp[0] + (float)NN * br[0];
}

// ---------------- launch ----------------
extern "C" void kernel_launch(void* const* d_in, const int* in_sizes, int n_in,
                              void* d_out, int out_size, void* d_ws, size_t ws_size,
                              hipStream_t stream) {
  const float* feats = (const float*)d_in[0];
  const int* src = (const int*)d_in[1];
  const int* dst = (const int*)d_in[2];
  const float* W1 = (const float*)d_in[3];
  const float* al1 = (const float*)d_in[4];
  const float* ar1 = (const float*)d_in[5];
  const float* b1 = (const float*)d_in[6];
  const float* W2 = (const float*)d_in[7];
  const float* al2 = (const float*)d_in[8];
  const float* ar2 = (const float*)d_in[9];
  const float* b2 = (const float*)d_in[10];
  const float* Wr = (const float*)d_in[11];
  const float* br = (const float*)d_in[12];
  float* out = (float*)d_out;

  // workspace layout (~33 MB); all section sizes multiples of 16 B
  __hip_bfloat16* featsb = (__hip_bfloat16*)d_ws;               // NN*128 bf16
  __hip_bfloat16* aggb = featsb + (size_t)NN * 128;             // MPAD*512 bf16
  __hip_bfloat16* W1t = aggb + (size_t)MPAD * HD;               // 512*128 bf16
  __hip_bfloat16* vcombh = W1t + 512 * 128;                     // 4*16*128 bf16
  float* wl1t = (float*)(vcombh + 4 * 16 * 128);                // 128*4 f32
  float* wr1t = wl1t + 512;                                     // 128*4 f32
  float* el1 = wr1t + 512;                                      // NN*4
  float* er1 = el1 + (size_t)NN * NHEAD;                        // NN*4
  float* elq = er1 + (size_t)NN * NHEAD;                        // NN*8
  float* er2 = elq + (size_t)NN * 8;                            // NN*4
  float* partials = er2 + (size_t)NN * NHEAD;                   // 256
  int* cnt = (int*)(partials + 256);                            // NN
  int* src_perm = cnt + NN;                                     // NN*SLOTS

  // prep: cnt zero + feats->bf16 + W1^T + vcombh + wl1t/wr1t + zeros
  prep_kernel<<<(S6 + 255) / 256, 256, 0, stream>>>(
      feats, W1, W2, al1, ar1, al2, ar2, Wr, featsb, W1t, vcombh, wl1t, wr1t,
      elq, partials, cnt);

  // CSR fill + layer-1 logits
  fill_logits_kernel<<<NN / 8, 256, 0, stream>>>(
      src, dst, cnt, src_perm, featsb, wl1t, wr1t, el1, er1);

  // layer-1 attn + FEATS aggregation (packed-f32 FMA)
  gather_kernel<<<NN / 4, 256, 0, stream>>>(featsb, cnt, src_perm, el1, er1,
                                            aggb);

  // agg @ W1 -> h1 (in-LDS) -> atomic combine into compact elq/er2
  dim3 h1grid(MPAD / 128, NHEAD);
  h1_gemm_kernel<<<h1grid, 256, 0, stream>>>(aggb, W1t, vcombh, b1, elq, er2);

  // layer-2 attention + readout dot; spread partials then tiny final reduce
  attn_q_kernel<<<NN / 4, 256, 0, stream>>>(src_perm, cnt, elq, er2, partials);
  final_kernel<<<1, 512, 0, stream>>>(partials, b2, Wr, br, out);
}